// Round 4
// baseline (413.067 us; speedup 1.0000x reference)
//
#include <hip/hip_runtime.h>

#define CH 256
#define HH 56
#define WW 56
#define HWSZ (HH*WW)            // 3136
#define WQ_ELEMS (CH*CH*9)      // 589824

#define IWN 64
#define XROW 2048               // shorts per input-row plane: 64 iw * 32 ic
#define XBUF (6*XROW)           // 12288 shorts per buffer (24.6 KB)
#define NCHUNK 1536             // 6 rows * 64 iw * 4 slots = 3 * 512 exactly

typedef short short8 __attribute__((ext_vector_type(8)));
typedef float f32x4 __attribute__((ext_vector_type(4)));

__device__ __forceinline__ unsigned short f2bf(float f) {
  unsigned u = __builtin_bit_cast(unsigned, f);
  u += 0x7FFFu + ((u >> 16) & 1u);   // round-to-nearest-even
  return (unsigned short)(u >> 16);
}

// ---------------- kernel 1: max(|w|), float4 ----------------
__global__ void absmax_kernel(const float4* __restrict__ w, unsigned* __restrict__ out) {
  int tid = blockIdx.x * 256 + threadIdx.x;
  float4 v = w[tid];
  float m = fmaxf(fmaxf(fabsf(v.x), fabsf(v.y)), fmaxf(fabsf(v.z), fabsf(v.w)));
  #pragma unroll
  for (int o = 32; o; o >>= 1) m = fmaxf(m, __shfl_xor(m, o, 64));
  if ((threadIdx.x & 63) == 0) atomicMax(out, __builtin_bit_cast(unsigned, m));
}

// ---------------- kernel 2: quantize -> bf16, layout [tap][ic-chunk][oc][32ic] ----------------
__global__ void quant_kernel(const float* __restrict__ w, const float* __restrict__ Wp,
                             const float* __restrict__ Wn, const unsigned* __restrict__ mx,
                             unsigned short* __restrict__ wq) {
  int o = blockIdx.x * 256 + threadIdx.x;
  int ic2 = o & 31, oc = (o >> 5) & 255, c = (o >> 13) & 7, k = o >> 16;
  int ic = c * 32 + ic2;
  float m = __builtin_bit_cast(float, *mx);
  float thr = 0.05f * m;
  float v = w[(oc * CH + ic) * 9 + k];
  float q = 0.f;
  if (m > 0.f) {
    if (v > thr) q = Wp[0];
    else if (v < -thr) q = -Wn[0];
  }
  wq[o] = f2bf(q);
}

// ---------------- kernel 3: conv ----------------
// Block = (n, 4 output rows) x 256 oc x 56 w; 512 thr = 8 waves = 2 oc-halves x 4 rows.
// Wave tile 128oc x 64w x 1 row: acc = 128 VGPR; launch_bounds(512,1) -> 256-reg budget.
// X in LDS (6 rows, dbuf, conflict-free swizzle); W global->VGPR (L1/L2-resident).
__global__ __launch_bounds__(512, 1)
void conv_kernel(const float* __restrict__ x, const unsigned short* __restrict__ wq,
                 const float* __restrict__ bias, float* __restrict__ out) {
  __shared__ __align__(16) unsigned short Xl[2 * XBUF];   // 49152 B

  const int tid  = threadIdx.x;
  const int lane = tid & 63;
  const int l15  = lane & 15;
  const int kg   = lane >> 4;      // 0..3 (ic octet within chunk)
  const int wid  = tid >> 6;       // 0..7
  const int och  = wid & 1;        // oc half (128 oc)
  const int wr   = wid >> 1;       // output row 0..3
  const int n    = blockIdx.x;
  const int h0   = blockIdx.y * 4;

  f32x4 acc[8][4];
  #pragma unroll
  for (int m = 0; m < 8; ++m)
    #pragma unroll
    for (int nc = 0; nc < 4; ++nc) acc[m][nc] = (f32x4)0.f;

  // ---- staging geometry: 3 chunks per thread, exact cover (1536 = 3*512) ----
  int goff[3], loff[3];
  bool ok[3];
  #pragma unroll
  for (int k = 0; k < 3; ++k) {
    int c    = tid + k * 512;
    int slot = c & 3;
    int q    = c >> 2;
    int iw   = q & 63;
    int r    = q >> 6;             // 0..5
    int hx = h0 + r - 1;
    int xw = iw - 1;
    ok[k] = ((unsigned)hx < (unsigned)HH) && ((unsigned)xw < (unsigned)WW);
    goff[k] = slot * 8 * HWSZ + (ok[k] ? (hx * WW + xw) : 0);
    loff[k] = r * XROW + iw * 32 + ((slot ^ ((iw >> 1) & 3)) * 8);
  }
  const float* xbase = x + (long)n * CH * HWSZ;

  // ---- precomputed B-read lane offsets (shorts), clamped (iw>63 feeds discarded w>=56 only)
  int boff[12];
  #pragma unroll
  for (int nc = 0; nc < 4; ++nc)
    #pragma unroll
    for (int kw = 0; kw < 3; ++kw) {
      int iw = nc * 16 + l15 + kw;
      if (iw > 63) iw = 63;
      boff[nc * 3 + kw] = iw * 32 + ((kg ^ ((iw >> 1) & 3)) * 8);
    }

  const int alane = (och * 128 + l15) * 32 + kg * 8;

  float xr[3][8];

  // ---- prologue: stage ic-chunk 0 into buffer 0 ----
  #pragma unroll
  for (int k = 0; k < 3; ++k)
    #pragma unroll
    for (int j = 0; j < 8; ++j)
      xr[k][j] = ok[k] ? xbase[goff[k] + j * HWSZ] : 0.f;
  #pragma unroll
  for (int k = 0; k < 3; ++k) {
    short8 p;
    #pragma unroll
    for (int j = 0; j < 8; ++j) p[j] = (short)f2bf(xr[k][j]);
    *(short8*)&Xl[loff[k]] = p;
  }
  __syncthreads();

  for (int t = 0; t < 8; ++t) {
    const int cur = (t & 1) * XBUF;
    const int nxt = XBUF - cur;

    // ---- issue next ic-chunk's global loads early (hide under MFMA) ----
    if (t < 7) {
      const int icn = (t + 1) * 32;
      #pragma unroll
      for (int k = 0; k < 3; ++k)
        #pragma unroll
        for (int j = 0; j < 8; ++j)
          xr[k][j] = ok[k] ? xbase[goff[k] + (icn + j) * HWSZ] : 0.f;
    }

    // ---- compute: 9 taps; A coalesced from global (L1/L2), B from LDS ----
    #pragma unroll
    for (int kh = 0; kh < 3; ++kh) {
      const int rxo = cur + (wr + kh) * XROW;
      #pragma unroll
      for (int kw = 0; kw < 3; ++kw) {
        const unsigned short* ap = wq + ((kh * 3 + kw) * 8 + t) * 8192 + alane;
        short8 a[8];
        #pragma unroll
        for (int m = 0; m < 8; ++m) a[m] = *(const short8*)(ap + m * 512);
        short8 b[4];
        #pragma unroll
        for (int nc = 0; nc < 4; ++nc) b[nc] = *(const short8*)&Xl[rxo + boff[nc * 3 + kw]];
        #pragma unroll
        for (int m = 0; m < 8; ++m)
          #pragma unroll
          for (int nc = 0; nc < 4; ++nc)
            acc[m][nc] = __builtin_amdgcn_mfma_f32_16x16x32_bf16(a[m], b[nc], acc[m][nc], 0, 0, 0);
      }
    }

    // ---- write staged chunk to the other buffer; one barrier per chunk ----
    if (t < 7) {
      #pragma unroll
      for (int k = 0; k < 3; ++k) {
        short8 p;
        #pragma unroll
        for (int j = 0; j < 8; ++j) p[j] = (short)f2bf(xr[k][j]);
        *(short8*)&Xl[nxt + loff[k]] = p;
      }
    }
    __syncthreads();
  }

  // ---- epilogue: D col = l15 (w), row = kg*4 + j (oc) ----
  const int h = h0 + wr;
  #pragma unroll
  for (int m = 0; m < 8; ++m) {
    const int ocb = och * 128 + m * 16 + kg * 4;
    #pragma unroll
    for (int nc = 0; nc < 4; ++nc) {
      const int w = nc * 16 + l15;
      if (w < WW) {
        float* op = out + ((long)(n * CH + ocb) * HH + h) * WW + w;
        #pragma unroll
        for (int j = 0; j < 4; ++j)
          op[(long)j * HWSZ] = acc[m][nc][j] + bias[ocb + j];
      }
    }
  }
}

extern "C" void kernel_launch(void* const* d_in, const int* in_sizes, int n_in,
                              void* d_out, int out_size, void* d_ws, size_t ws_size,
                              hipStream_t stream) {
  const float* x      = (const float*)d_in[0];
  const float* weight = (const float*)d_in[1];
  const float* bias   = (const float*)d_in[2];
  const float* Wp     = (const float*)d_in[3];
  const float* Wn     = (const float*)d_in[4];
  float* out          = (float*)d_out;

  unsigned* mx        = (unsigned*)d_ws;
  unsigned short* wqp = (unsigned short*)((char*)d_ws + 64);

  hipMemsetAsync(d_ws, 0, 64, stream);
  absmax_kernel<<<WQ_ELEMS / 4 / 256, 256, 0, stream>>>((const float4*)weight, mx);
  quant_kernel<<<WQ_ELEMS / 256, 256, 0, stream>>>(weight, Wp, Wn, mx, wqp);
  conv_kernel<<<dim3(32, HH / 4), 512, 0, stream>>>(x, wqp, bias, out);
}

// Round 5
// 197.718 us; speedup vs baseline: 2.0892x; 2.0892x over previous
//
#include <hip/hip_runtime.h>

#define CH 256
#define HH 56
#define WW 56
#define HWSZ 3136
#define WQ_ELEMS (CH*CH*9)      // 589824

#define XROW 2048               // shorts: 64 iw * 32 ic
#define XBUF (6*XROW)           // 12288 shorts per X buffer
#define WBUF 24576              // shorts: 3 kw * 256 oc * 32 ic per W buffer

typedef short short8 __attribute__((ext_vector_type(8)));
typedef float f32x4 __attribute__((ext_vector_type(4)));
typedef __attribute__((address_space(3))) unsigned short as3_ushort;
typedef __attribute__((address_space(1))) const unsigned short as1_ushort;

__device__ __forceinline__ unsigned short f2bf(float f) {
  unsigned u = __builtin_bit_cast(unsigned, f);
  u += 0x7FFFu + ((u >> 16) & 1u);   // round-to-nearest-even
  return (unsigned short)(u >> 16);
}

// ---------------- kernel 1: max(|w|), float4 ----------------
__global__ void absmax_kernel(const float4* __restrict__ w, unsigned* __restrict__ out) {
  int tid = blockIdx.x * 256 + threadIdx.x;
  float4 v = w[tid];
  float m = fmaxf(fmaxf(fabsf(v.x), fabsf(v.y)), fmaxf(fabsf(v.z), fabsf(v.w)));
  #pragma unroll
  for (int o = 32; o; o >>= 1) m = fmaxf(m, __shfl_xor(m, o, 64));
  if ((threadIdx.x & 63) == 0) atomicMax(out, __builtin_bit_cast(unsigned, m));
}

// ---------------- kernel 2: quantize -> bf16, layout [tap][ic-chunk][oc][32ic] ----------------
__global__ void quant_kernel(const float* __restrict__ w, const float* __restrict__ Wp,
                             const float* __restrict__ Wn, const unsigned* __restrict__ mx,
                             unsigned short* __restrict__ wq) {
  int o = blockIdx.x * 256 + threadIdx.x;
  int ic2 = o & 31, oc = (o >> 5) & 255, c = (o >> 13) & 7, k = o >> 16;
  int ic = c * 32 + ic2;
  float m = __builtin_bit_cast(float, *mx);
  float thr = 0.05f * m;
  float v = w[(oc * CH + ic) * 9 + k];
  float q = 0.f;
  if (m > 0.f) {
    if (v > thr) q = Wp[0];
    else if (v < -thr) q = -Wn[0];
  }
  wq[o] = f2bf(q);
}

// ---------------- kernel 3: conv ----------------
// Block = (n, 4 output rows); 8 waves = 2 oc-halves x 4 rows; wave tile 128oc x 64w.
// W staged global->LDS via global_load_lds (dbuf per (t,kh) step, linear layout,
// conflict-free A-read); X staged reg->LDS (dbuf per t, zero-conflict swizzle).
__global__ __launch_bounds__(512, 2)
void conv_kernel(const float* __restrict__ x, const unsigned short* __restrict__ wq,
                 const float* __restrict__ bias, float* __restrict__ out) {
  extern __shared__ __align__(16) unsigned short lds[];
  unsigned short* Wl = lds;              // 2 * WBUF shorts (96 KB)
  unsigned short* Xl = lds + 2 * WBUF;   // 2 * XBUF shorts (48 KB)

  const int tid  = threadIdx.x;
  const int lane = tid & 63;
  const int l15  = lane & 15;
  const int kg   = lane >> 4;      // 0..3 (ic octet)
  const int wid  = tid >> 6;       // 0..7
  const int och  = wid & 1;        // oc half (128 oc)
  const int wr   = wid >> 1;       // output row 0..3
  const int n    = blockIdx.x;
  const int h0   = blockIdx.y * 4;

  f32x4 acc[8][4];
  #pragma unroll
  for (int m = 0; m < 8; ++m)
    #pragma unroll
    for (int nc = 0; nc < 4; ++nc) acc[m][nc] = (f32x4)0.f;

  // ---- X staging geometry: 3 chunks/thread (1536 = 3*512) ----
  int goff[3], loff[3];
  bool ok[3];
  #pragma unroll
  for (int k = 0; k < 3; ++k) {
    int c    = tid + k * 512;
    int slot = c & 3;
    int q    = c >> 2;
    int iw   = q & 63;
    int r    = q >> 6;             // 0..5
    int hx = h0 + r - 1;
    int xw = iw - 1;
    ok[k] = ((unsigned)hx < (unsigned)HH) && ((unsigned)xw < (unsigned)WW);
    goff[k] = slot * 8 * HWSZ + (ok[k] ? (hx * WW + xw) : 0);
    loff[k] = r * XROW + iw * 32 + ((slot ^ ((iw >> 1) & 3)) * 8);
  }
  const float* xbase = x + (long)n * CH * HWSZ;

  // ---- B-read offsets (zero-conflict swizzle, measured) ----
  int boff[12];
  #pragma unroll
  for (int nc = 0; nc < 4; ++nc)
    #pragma unroll
    for (int kw = 0; kw < 3; ++kw) {
      int iw = nc * 16 + l15 + kw;
      if (iw > 63) iw = 63;        // feeds only discarded w >= 56
      boff[nc * 3 + kw] = iw * 32 + ((kg ^ ((iw >> 1) & 3)) * 8);
    }

  const int aoff = (och * 128 + l15) * 32 + kg * 8;   // A-read lane offset within kw region

  // ---- W-stage: 48 x 1KB wave-issues per step; wave w takes g = i*8+w ----
  auto stageW = [&](int s) {
    const int tt = s / 3, kh = s - tt * 3;
    const int base = (s & 1) * WBUF;
    #pragma unroll
    for (int i = 0; i < 6; ++i) {
      const int g   = i * 8 + wid;       // 0..47
      const int kw  = g >> 4;
      const int sub = g & 15;
      const unsigned short* src = wq + (((kh * 3 + kw) * 8 + tt) * 8192) + sub * 512 + lane * 8;
      unsigned short* dst = Wl + base + kw * 8192 + sub * 512;   // wave-uniform
      __builtin_amdgcn_global_load_lds((as1_ushort*)src, (as3_ushort*)dst, 16, 0, 0);
    }
  };

  float xr[3][8];

  // ---- prologue: X(t=0) loads, W(step 0) stage, X write, barrier ----
  #pragma unroll
  for (int k = 0; k < 3; ++k)
    #pragma unroll
    for (int j = 0; j < 8; ++j)
      xr[k][j] = ok[k] ? xbase[goff[k] + j * HWSZ] : 0.f;
  stageW(0);
  #pragma unroll
  for (int k = 0; k < 3; ++k) {
    short8 p;
    #pragma unroll
    for (int j = 0; j < 8; ++j) p[j] = (short)f2bf(xr[k][j]);
    *(short8*)&Xl[loff[k]] = p;
  }
  __syncthreads();

  for (int t = 0; t < 8; ++t) {
    const int xcur = (t & 1) * XBUF;
    const int xnxt = XBUF - xcur;
    #pragma unroll
    for (int kh = 0; kh < 3; ++kh) {
      const int s = t * 3 + kh;

      // issue next step's W stage (lands under this step's MFMAs, drained at barrier)
      if (s < 23) stageW(s + 1);

      // issue next ic-chunk's X loads at kh==0 (HBM latency hidden by 2 steps)
      if (kh == 0 && t < 7) {
        const int icn = (t + 1) * 32;
        #pragma unroll
        for (int k = 0; k < 3; ++k)
          #pragma unroll
          for (int j = 0; j < 8; ++j)
            xr[k][j] = ok[k] ? xbase[goff[k] + (icn + j) * HWSZ] : 0.f;
      }

      // compute: 3 kw taps; A + B both from LDS
      const int wb  = (s & 1) * WBUF;
      const int rxo = xcur + (wr + kh) * XROW;
      #pragma unroll
      for (int kw = 0; kw < 3; ++kw) {
        const unsigned short* ap = Wl + wb + kw * 8192 + aoff;
        short8 a[8];
        #pragma unroll
        for (int m = 0; m < 8; ++m) a[m] = *(const short8*)(ap + m * 512);
        short8 b[4];
        #pragma unroll
        for (int nc = 0; nc < 4; ++nc) b[nc] = *(const short8*)&Xl[rxo + boff[nc * 3 + kw]];
        #pragma unroll
        for (int m = 0; m < 8; ++m)
          #pragma unroll
          for (int nc = 0; nc < 4; ++nc)
            acc[m][nc] = __builtin_amdgcn_mfma_f32_16x16x32_bf16(a[m], b[nc], acc[m][nc], 0, 0, 0);
      }

      // write next X chunk into the other X buffer at kh==1 (loads drained at kh==0 barrier)
      if (kh == 1 && t < 7) {
        #pragma unroll
        for (int k = 0; k < 3; ++k) {
          short8 p;
          #pragma unroll
          for (int j = 0; j < 8; ++j) p[j] = (short)f2bf(xr[k][j]);
          *(short8*)&Xl[xnxt + loff[k]] = p;
        }
      }
      __syncthreads();
    }
  }

  // ---- epilogue: D col = l15 (w), row = kg*4 + j (oc) ----
  const int h = h0 + wr;
  #pragma unroll
  for (int m = 0; m < 8; ++m) {
    const int ocb = och * 128 + m * 16 + kg * 4;
    #pragma unroll
    for (int nc = 0; nc < 4; ++nc) {
      const int w = nc * 16 + l15;
      if (w < WW) {
        float* op = out + ((long)(n * CH + ocb) * HH + h) * WW + w;
        #pragma unroll
        for (int j = 0; j < 4; ++j)
          op[(long)j * HWSZ] = acc[m][nc][j] + bias[ocb + j];
      }
    }
  }
}

extern "C" void kernel_launch(void* const* d_in, const int* in_sizes, int n_in,
                              void* d_out, int out_size, void* d_ws, size_t ws_size,
                              hipStream_t stream) {
  const float* x      = (const float*)d_in[0];
  const float* weight = (const float*)d_in[1];
  const float* bias   = (const float*)d_in[2];
  const float* Wp     = (const float*)d_in[3];
  const float* Wn     = (const float*)d_in[4];
  float* out          = (float*)d_out;

  unsigned* mx        = (unsigned*)d_ws;
  unsigned short* wqp = (unsigned short*)((char*)d_ws + 64);

  static const int LDS_BYTES = 2 * (WBUF + XBUF) * 2;   // 147456
  hipFuncSetAttribute((const void*)conv_kernel,
                      hipFuncAttributeMaxDynamicSharedMemorySize, LDS_BYTES);

  hipMemsetAsync(d_ws, 0, 64, stream);
  absmax_kernel<<<WQ_ELEMS / 4 / 256, 256, 0, stream>>>((const float4*)weight, mx);
  quant_kernel<<<WQ_ELEMS / 256, 256, 0, stream>>>(weight, Wp, Wn, mx, wqp);
  conv_kernel<<<dim3(32, HH / 4), 512, LDS_BYTES, stream>>>(x, wqp, bias, out);
}